// Round 14
// baseline (426.716 us; speedup 1.0000x reference)
//
#include <hip/hip_runtime.h>
#include <hip/hip_bf16.h>

#define H 8
#define C 16
#define HC 128          // H*C
#define NEG 0.2f
#define XS_S 132        // LDS row stride (floats) for k1 x-tile

#define ANSH 6          // 64 nodes per fine aggregation bucket
#define AN 64
#define AMSK 63
#define CAP2 2560       // pairs2 capacity per fine bucket (mean 2048, +11 sigma)
#define MAXB2 2048      // fine bucket cap: N <= 131072
#define CB_SH 12        // 4096 nodes per coarse bucket
#define CBMSK 4095
#define MAXB1 64        // coarse bucket cap (src packs in 17b: N <= 131072)
#define EPB 4096        // edges per binning chunk (16 edges/thread @ 256 thr)
#define NTL 8           // src tiles (16384 nodes = 4 MB of h16 = one XCD L2)
#define TL_SH 14

// exact: for x>=0 max returns x, for x<0 returns 0.2x  (2 VALU, no cndmask)
__device__ __forceinline__ float lrelu(float x) { return fmaxf(x, NEG * x); }

__device__ __forceinline__ unsigned pack_bf16(float a, float b) {
    union { __hip_bfloat16 h; unsigned short u; } ua, ub;
    ua.h = __float2bfloat16(a);
    ub.h = __float2bfloat16(b);
    return (unsigned)ua.u | ((unsigned)ub.u << 16);
}
__device__ __forceinline__ float bf_lo(unsigned d) { return __uint_as_float(d << 16); }
__device__ __forceinline__ float bf_hi(unsigned d) { return __uint_as_float(d & 0xffff0000u); }

// K1: h = x @ W, fp32 register-tiled GEMM, bf16-packed output (proven).
// Epilogue also computes a_src/a_dst (width-4 shfl reduce).
__global__ void __launch_bounds__(256) k1_gemm(const float* __restrict__ x,
                                               const float* __restrict__ W,
                                               const float* __restrict__ att_src,
                                               const float* __restrict__ att_dst,
                                               unsigned* __restrict__ h16,
                                               float* __restrict__ a_src,
                                               float* __restrict__ a_dst, int N) {
    __shared__ float xs[64 * XS_S];
    const int n0 = blockIdx.x * 64;
    const int t = threadIdx.x;
#pragma unroll
    for (int i = 0; i < 8; ++i) {
        int id = t + 256 * i;           // 2048 float4-chunks
        int r = id >> 5, kq = id & 31;
        int n = n0 + r;
        float4 v = (n < N) ? ((const float4*)x)[(size_t)n * 32 + kq]
                           : make_float4(0.f, 0.f, 0.f, 0.f);
        *(float4*)&xs[r * XS_S + kq * 4] = v;
    }
    __syncthreads();
    const int cg = t & 31;        // cols cg*4..+3
    const int r0 = (t >> 5) * 8;  // rows r0..r0+7
    float acc[8][4];
#pragma unroll
    for (int i = 0; i < 8; ++i)
#pragma unroll
        for (int j = 0; j < 4; ++j) acc[i][j] = 0.f;

#pragma unroll 4
    for (int k = 0; k < HC; ++k) {
        const float4 wv = ((const float4*)W)[k * 32 + cg];
        float wr[4] = {wv.x, wv.y, wv.z, wv.w};
#pragma unroll
        for (int i = 0; i < 8; ++i) {
            float xv = xs[(r0 + i) * XS_S + k];   // broadcast across cg lanes
#pragma unroll
            for (int j = 0; j < 4; ++j) acc[i][j] += xv * wr[j];
        }
    }
    const int fhd = cg >> 2;       // head owning this lane's 4 cols
    const int cq  = cg & 3;        // quarter within the head's 16 cols
#pragma unroll
    for (int i = 0; i < 8; ++i) {
        int n = n0 + r0 + i;
        if (n < N) {
            uint2 dv = make_uint2(pack_bf16(acc[i][0], acc[i][1]),
                                  pack_bf16(acc[i][2], acc[i][3]));
            *(uint2*)&h16[(size_t)n * 64 + cg * 2] = dv;
        }
        float ps = 0.f, pd = 0.f;
#pragma unroll
        for (int jj = 0; jj < 4; ++jj) {
            float hv = acc[i][jj];
            ps += hv * att_src[fhd * C + cq * 4 + jj];
            pd += hv * att_dst[fhd * C + cq * 4 + jj];
        }
        ps += __shfl_xor(ps, 1, 4); pd += __shfl_xor(pd, 1, 4);
        ps += __shfl_xor(ps, 2, 4); pd += __shfl_xor(pd, 2, 4);
        if (cq == 0 && n < N) {
            a_src[(unsigned)n * 8u + fhd] = ps;
            a_dst[(unsigned)n * 8u + fhd] = pd;
        }
    }
}

// KB_BIN1: coarse binning (25 buckets of 4096 nodes). Single-read,
// register-resident, direct global scatter via per-(wave,bucket) cursors
// (R13 version, proven). Pack: src(17b) | (dst & 4095) << 17.
__global__ void __launch_bounds__(256) kb_bin1(const int* __restrict__ ei,
                                               int* __restrict__ gcount1,
                                               unsigned* __restrict__ pairs1,
                                               int E, int NB1, int cap1) {
    __shared__ int hist[4][MAXB1];
    __shared__ int cur[4][MAXB1];      // GLOBAL cursor per (wave,bucket)
    __shared__ int tot[MAXB1];
    __shared__ int scn[MAXB1];
    const int t = threadIdx.x;
    const int wv = t >> 6;
    const int e0 = blockIdx.x * EPB;
    const int nE = min(EPB, E - e0);
    ((int*)hist)[t] = 0;               // 4*64 == 256
    __syncthreads();

    const bool al4 = ((E & 3) == 0);
    const int nE4 = nE >> 2;
    int4 dreg[4], sreg[4];
    const int4* d4p = (const int4*)(ei + E + e0);
    const int4* s4p = (const int4*)(ei + e0);
#pragma unroll
    for (int j = 0; j < 4; ++j) {
        int idx = j * 256 + t;
        if (idx < nE4) {
            if (al4) { dreg[j] = d4p[idx]; sreg[j] = s4p[idx]; }
            else {
                int e = idx * 4;
                dreg[j] = make_int4(ei[E + e0 + e], ei[E + e0 + e + 1],
                                    ei[E + e0 + e + 2], ei[E + e0 + e + 3]);
                sreg[j] = make_int4(ei[e0 + e], ei[e0 + e + 1],
                                    ei[e0 + e + 2], ei[e0 + e + 3]);
            }
        }
    }
    int tlD = 0, tlS = -1;             // scalar tail (<=3 edges)
    {
        int tb = nE4 * 4 + t;
        if (tb < nE) { tlD = ei[E + e0 + tb]; tlS = ei[e0 + tb]; }
    }
#pragma unroll
    for (int j = 0; j < 4; ++j) {
        if (j * 256 + t < nE4) {
            atomicAdd(&hist[wv][dreg[j].x >> CB_SH], 1);
            atomicAdd(&hist[wv][dreg[j].y >> CB_SH], 1);
            atomicAdd(&hist[wv][dreg[j].z >> CB_SH], 1);
            atomicAdd(&hist[wv][dreg[j].w >> CB_SH], 1);
        }
    }
    if (tlS >= 0) atomicAdd(&hist[wv][tlD >> CB_SH], 1);
    __syncthreads();
    if (t < MAXB1) {
        int s = 0;
#pragma unroll
        for (int w = 0; w < 4; ++w) s += hist[w][t];
        tot[t] = s;
        scn[t] = s;
    }
    __syncthreads();
    for (int off = 1; off < MAXB1; off <<= 1) {
        int v = (t < MAXB1 && t >= off) ? scn[t - off] : 0;
        __syncthreads();
        if (t < MAXB1) scn[t] += v;
        __syncthreads();
    }
    if (t < MAXB1) {
        int h = tot[t];
        int gb = h ? t * cap1 + atomicAdd(&gcount1[t], h) : 0;
#pragma unroll
        for (int w = 0; w < 4; ++w) { cur[w][t] = gb; gb += hist[w][t]; }
    }
    __syncthreads();
#pragma unroll
    for (int j = 0; j < 4; ++j) {
        if (j * 256 + t < nE4) {
#pragma unroll
            for (int q = 0; q < 4; ++q) {
                int dst = (&dreg[j].x)[q], src = (&sreg[j].x)[q];
                int b = dst >> CB_SH;
                int pos = atomicAdd(&cur[wv][b], 1);
                if (pos < b * cap1 + cap1)
                    pairs1[pos] = (unsigned)src | ((unsigned)(dst & CBMSK) << 17);
            }
        }
    }
    if (tlS >= 0) {
        int b = tlD >> CB_SH;
        int pos = atomicAdd(&cur[wv][b], 1);
        if (pos < b * cap1 + cap1)
            pairs1[pos] = (unsigned)tlS | ((unsigned)(tlD & CBMSK) << 17);
    }
}

// KB_BIN2: fine binning within a coarse region (R13 version, proven).
// Repack to src | ldst6<<18.
__global__ void __launch_bounds__(256) kb_bin2(const unsigned* __restrict__ pairs1,
                                               const int* __restrict__ gcount1,
                                               int* __restrict__ gcount2,
                                               unsigned* __restrict__ pairs2,
                                               int cap1, int ch2) {
    __shared__ int hist[4][64];
    __shared__ int cur[4][64];         // GLOBAL cursor per (wave,bucket)
    __shared__ int tot[64];
    const int cb = blockIdx.x / ch2;
    const int ci = blockIdx.x % ch2;
    const int c1 = min(gcount1[cb], cap1);
    const int e0 = ci * EPB;
    if (e0 >= c1) return;              // uniform exit
    const int nE = min(EPB, c1 - e0);
    const unsigned b1 = (unsigned)cb * (unsigned)cap1 + (unsigned)e0;
    const int t = threadIdx.x;
    const int wv = t >> 6;
    ((int*)hist)[t] = 0;               // 4*64 == 256
    __syncthreads();

    const int nE4 = nE >> 2;           // b1 is 16B-aligned (cap1, EPB %4==0)
    const uint4* p4 = (const uint4*)(pairs1 + b1);
    uint4 preg[4];
#pragma unroll
    for (int j = 0; j < 4; ++j) {
        int idx = j * 256 + t;
        if (idx < nE4) preg[j] = p4[idx];
    }
    unsigned tlP = 0; int tlV = 0;     // scalar tail (<=3 edges)
    {
        int tb = nE4 * 4 + t;
        if (tb < nE) { tlP = pairs1[b1 + tb]; tlV = 1; }
    }
#pragma unroll
    for (int j = 0; j < 4; ++j) {
        if (j * 256 + t < nE4) {
            atomicAdd(&hist[wv][preg[j].x >> 23], 1);
            atomicAdd(&hist[wv][preg[j].y >> 23], 1);
            atomicAdd(&hist[wv][preg[j].z >> 23], 1);
            atomicAdd(&hist[wv][preg[j].w >> 23], 1);
        }
    }
    if (tlV) atomicAdd(&hist[wv][tlP >> 23], 1);
    __syncthreads();
    if (t < 64) {
        int s = 0;
#pragma unroll
        for (int w = 0; w < 4; ++w) s += hist[w][t];
        tot[t] = s;
    }
    __syncthreads();
    if (t < 64) {
        int h = tot[t];
        int gfb = cb * 64 + t;
        int gb = h ? gfb * CAP2 + atomicAdd(&gcount2[gfb], h) : 0;
#pragma unroll
        for (int w = 0; w < 4; ++w) { cur[w][t] = gb; gb += hist[w][t]; }
    }
    __syncthreads();
#pragma unroll
    for (int j = 0; j < 4; ++j) {
        if (j * 256 + t < nE4) {
#pragma unroll
            for (int q = 0; q < 4; ++q) {
                unsigned pv = (&preg[j].x)[q];
                int fb = pv >> 23;
                int pos = atomicAdd(&cur[wv][fb], 1);
                if (pos < (cb * 64 + fb) * CAP2 + CAP2)
                    pairs2[pos] = (pv & 0x1FFFFu) | (((pv >> 17) & 63u) << 18);
            }
        }
    }
    if (tlV) {
        int fb = tlP >> 23;
        int pos = atomicAdd(&cur[wv][fb], 1);
        if (pos < (cb * 64 + fb) * CAP2 + CAP2)
            pairs2[pos] = (tlP & 0x1FFFFu) | (((tlP >> 17) & 63u) << 18);
    }
}

// K_FUSED: one block per 64-node fine bucket, 512 threads.
// NEW: edges counting-sorted by key = node*8 + src_tile (tile = src>>14,
// 4 MB of h16 = one XCD L2). Aggregation sweeps the 8 src-tiles in a
// block-synchronous outer loop (barrier per tile) so all resident waves
// gather from the same 4 MB slice simultaneously -> the slice stays hot in
// every XCD's L2 and the 11x h16 re-fetch (506 MB vs 25.6 MB) collapses.
// Per-node accumulators live in LDS (wave-exclusive -> plain RMW per
// FRAGMENT, no atomics). 4-wide ds_bpermute w-dedup kept per fragment.
__global__ void __launch_bounds__(512) k_fused(const unsigned* __restrict__ pairs,
                                               const int* __restrict__ gcount,
                                               const unsigned* __restrict__ h16,
                                               const float* __restrict__ a_src,
                                               const float* __restrict__ a_dst,
                                               const float* __restrict__ bias,
                                               float* __restrict__ out, int N) {
    __shared__ int cnt[AN * NTL];      // 512 keys
    __shared__ int sc[AN * NTL];       // inclusive scan (kept for bounds)
    __shared__ int lcur[AN * NTL];
    __shared__ unsigned scol[CAP2];
    __shared__ float2 st[AN * 64];     // 32 KB accumulator state
    __shared__ float ssum[AN * 8];     // per (node,head) weight sum
    const int b = blockIdx.x;
    const int t = threadIdx.x;
    const int n0 = b << ANSH;
    const unsigned base = (unsigned)b * (unsigned)CAP2;
    const int cb = min(gcount[b], CAP2);

    cnt[t] = 0;
    ssum[t] = 0.f;                     // AN*8 == 512
    for (int i = t; i < AN * 64; i += 512) st[i] = make_float2(0.f, 0.f);
    __syncthreads();
    for (int j = t; j < cb; j += 512) {
        unsigned pv = pairs[base + j];
        int key = (int)((pv >> 18) * NTL + ((pv & 0x3FFFFu) >> TL_SH));
        atomicAdd(&cnt[key], 1);
    }
    __syncthreads();
    sc[t] = cnt[t];
    __syncthreads();
    for (int off = 1; off < AN * NTL; off <<= 1) {
        int v = (t >= off) ? sc[t - off] : 0;
        __syncthreads();
        sc[t] += v;
        __syncthreads();
    }
    lcur[t] = sc[t] - cnt[t];
    __syncthreads();
    for (int j = t; j < cb; j += 512) {
        unsigned pv = pairs[base + j];
        int key = (int)((pv >> 18) * NTL + ((pv & 0x3FFFFu) >> TL_SH));
        int pos = atomicAdd(&lcur[key], 1);
        scol[pos] = pv & 0x3FFFFu;
    }
    __syncthreads();

    const int wv = t >> 6;          // wave 0..7, owns nodes wv, wv+8, ...
    const int lane = t & 63;
    const int hd = lane >> 3;       // lane's head (channels 2*lane, 2*lane+1)
    const int hw = lane & 7;        // head of the pair this lane computes
    const int bidx = hd * 4;        // bpermute byte index, edge slot 0

    for (int s = 0; s < NTL; ++s) {
        for (int nl = wv; nl < AN; nl += 8) {
            const int key = nl * NTL + s;
            const int beg = key ? sc[key - 1] : 0;
            const int end = sc[key];
            const int node = n0 + nl;
            if (beg >= end || node >= N) continue;
            float2 stv = st[nl * 64 + lane];
            float sacc = 0.f;
            const float adst_own = a_dst[(unsigned)node * 8u + (unsigned)hd];
            const float adst_hh  = a_dst[(unsigned)node * 8u + (unsigned)hw];
            int j = beg;
            for (; j + 4 <= end; j += 4) {
                unsigned m0 = scol[j], m1 = scol[j + 1];
                unsigned m2 = scol[j + 2], m3 = scol[j + 3];
                unsigned nP = scol[j + ((lane >> 3) & 3)];
                float wme = __expf(lrelu(a_src[nP * 8u + (unsigned)hw] + adst_hh));
                int wi = __float_as_int(wme);
                float w0 = __int_as_float(__builtin_amdgcn_ds_bpermute(bidx,      wi));
                float w1 = __int_as_float(__builtin_amdgcn_ds_bpermute(bidx + 32, wi));
                float w2 = __int_as_float(__builtin_amdgcn_ds_bpermute(bidx + 64, wi));
                float w3 = __int_as_float(__builtin_amdgcn_ds_bpermute(bidx + 96, wi));
                unsigned d0 = h16[m0 * 64u + (unsigned)lane];
                unsigned d1 = h16[m1 * 64u + (unsigned)lane];
                unsigned d2 = h16[m2 * 64u + (unsigned)lane];
                unsigned d3 = h16[m3 * 64u + (unsigned)lane];
                stv.x += bf_lo(d0) * w0; stv.y += bf_hi(d0) * w0;
                stv.x += bf_lo(d1) * w1; stv.y += bf_hi(d1) * w1;
                stv.x += bf_lo(d2) * w2; stv.y += bf_hi(d2) * w2;
                stv.x += bf_lo(d3) * w3; stv.y += bf_hi(d3) * w3;
                sacc += w0 + w1 + w2 + w3;
            }
            for (; j < end; ++j) {
                unsigned mA = scol[j];
                float wA = __expf(lrelu(a_src[mA * 8u + (unsigned)hd] + adst_own));
                unsigned dA = h16[mA * 64u + (unsigned)lane];
                stv.x += bf_lo(dA) * wA; stv.y += bf_hi(dA) * wA;
                sacc += wA;
            }
            st[nl * 64 + lane] = stv;
            if ((lane & 7) == 0) ssum[nl * 8 + hd] += sacc;  // wave-exclusive
        }
        __syncthreads();   // keep the block's waves phase-aligned on tiles
    }

    for (int nl = wv; nl < AN; nl += 8) {
        const int node = n0 + nl;
        if (node >= N) continue;
        float wself = __expf(lrelu(a_src[(unsigned)node * 8u + (unsigned)hd] +
                                   a_dst[(unsigned)node * 8u + (unsigned)hd]));
        unsigned dsf = h16[(unsigned)node * 64u + (unsigned)lane];
        float2 stv = st[nl * 64 + lane];
        float inv = 1.f / (ssum[nl * 8 + hd] + wself + 1e-16f);
        float2 bv = ((const float2*)bias)[lane];
        float2 o;
        o.x = (stv.x + bf_lo(dsf) * wself) * inv + bv.x;
        o.y = (stv.y + bf_hi(dsf) * wself) * inv + bv.y;
        ((float2*)out)[(unsigned)node * 64u + (unsigned)lane] = o;
    }
}

extern "C" void kernel_launch(void* const* d_in, const int* in_sizes, int n_in,
                              void* d_out, int out_size, void* d_ws, size_t ws_size,
                              hipStream_t stream) {
    const float* x       = (const float*)d_in[0];
    const int*   ei      = (const int*)d_in[1];
    const float* W       = (const float*)d_in[2];
    const float* att_src = (const float*)d_in[3];
    const float* att_dst = (const float*)d_in[4];
    const float* bias    = (const float*)d_in[5];
    float* out = (float*)d_out;

    const int N = in_sizes[0] / HC;
    const int E = in_sizes[1] / 2;
    const int B = (N + AMSK) >> ANSH;            // fine buckets (<= MAXB2)
    const int NB1 = (N + CBMSK) >> CB_SH;        // coarse buckets (<= MAXB1)
    const int nbin = (E + EPB - 1) / EPB;
    const int cap1 = (((E + NB1 - 1) / NB1) + 32768 + 3) & ~3;  // coarse capacity
    const int ch2 = (cap1 + EPB - 1) / EPB;      // level-2 chunks per coarse

    // ws: h16[N*64]u32 | a_src[N*8]f | a_dst[N*8]f | gcount1[64] |
    //     gcount2[MAXB2] | pairs1[NB1*cap1] | pairs2[B*CAP2]
    unsigned* h16 = (unsigned*)d_ws;
    float* a_src  = (float*)(h16 + (size_t)N * 64);
    float* a_dst  = a_src + (size_t)N * H;
    int* gcount1  = (int*)(a_dst + (size_t)N * H);
    int* gcount2  = gcount1 + MAXB1;
    unsigned* pairs1 = (unsigned*)(gcount2 + MAXB2);
    unsigned* pairs2 = pairs1 + (size_t)NB1 * (size_t)cap1;

    (void)hipMemsetAsync(gcount1, 0, (MAXB1 + MAXB2) * sizeof(int), stream);
    kb_bin1<<<nbin, 256, 0, stream>>>(ei, gcount1, pairs1, E, NB1, cap1);
    kb_bin2<<<NB1 * ch2, 256, 0, stream>>>(pairs1, gcount1, gcount2, pairs2,
                                           cap1, ch2);
    k1_gemm<<<(N + 63) / 64, 256, 0, stream>>>(x, W, att_src, att_dst,
                                               h16, a_src, a_dst, N);
    k_fused<<<B, 512, 0, stream>>>(pairs2, gcount2, h16, a_src,
                                   a_dst, bias, out, N);
}